// Round 10
// baseline (609.348 us; speedup 1.0000x reference)
//
#include <hip/hip_runtime.h>
#include <hip/hip_bf16.h>

constexpr int DIM   = 1024;
constexpr int HEADS = 8;
constexpr int HD    = 128;     // head dim
constexpr int SEQ   = 2048;
constexpr int BATCH = 4;
constexpr int BN_ROWS = BATCH * SEQ;          // 8192
// Reference multiplies scores by sqrt(head_dim) (replicating that bug exactly).
#define SCALE_F 11.3137084989847603904f

typedef __attribute__((ext_vector_type(8))) short  short8;
typedef __attribute__((ext_vector_type(4))) float  f32x4;

// ---------------------------------------------------------------------------
// bf16 helpers
// ---------------------------------------------------------------------------
__device__ __forceinline__ ushort split_hi(float x, float& rem) {
    unsigned xb = __builtin_bit_cast(unsigned, x);
    unsigned hb = xb & 0xFFFF0000u;
    rem = x - __builtin_bit_cast(float, hb);
    return (ushort)(xb >> 16);
}
__device__ __forceinline__ ushort rne16(float x) {
    unsigned xb = __builtin_bit_cast(unsigned, x);
    unsigned r  = xb + 0x7FFFu + ((xb >> 16) & 1u);
    return (ushort)(r >> 16);
}
__device__ __forceinline__ void gload16(const void* g, void* l) {
    __builtin_amdgcn_global_load_lds(
        (const __attribute__((address_space(1))) void*)g,
        (__attribute__((address_space(3))) void*)l, 16, 0, 0);
}

// ---------------------------------------------------------------------------
// Split-bf16 MFMA GEMM core (R4-verified).  Used for out-proj unchanged;
// QKV variant below writes split-plane outputs instead of f32.
// NOTE: all pragmas inside macro args must use _Pragma() operator form.
// ---------------------------------------------------------------------------
constexpr int GS = 40;   // LDS row stride in bf16 elems

#define GEMM_BODY(EPILOGUE)                                                      \
    __shared__ ushort Ah[128 * GS], Al[128 * GS];                                \
    __shared__ ushort Bh[128 * GS], Bl[128 * GS];                                \
    const int tid  = threadIdx.x;                                                \
    const int lane = tid & 63;                                                   \
    const int w    = tid >> 6;                                                   \
    const int l15  = lane & 15;                                                  \
    const int g    = lane >> 4;                                                  \
    const int nbn   = N >> 7;                                                    \
    const int nb    = (M >> 7) * nbn;                                            \
    const int chunk = nb >> 3;                                                   \
    const int pid   = blockIdx.x;                                                \
    const int lb    = (pid & 7) * chunk + (pid >> 3);                            \
    const int m0    = (lb / nbn) * 128;                                          \
    const int n0    = (lb % nbn) * 128;                                          \
    const int mw = (w >> 1) * 64;                                                \
    const int nw = (w & 1) * 64;                                                 \
    const int srow = tid >> 1;                                                   \
    const int scol = (tid & 1) * 16;                                             \
    f32x4 acc[4][4];                                                             \
    _Pragma("unroll") for (int i = 0; i < 4; ++i)                                \
        _Pragma("unroll") for (int j = 0; j < 4; ++j)                            \
            acc[i][j] = (f32x4){0.f, 0.f, 0.f, 0.f};                             \
    for (int k0 = 0; k0 < K; k0 += 32) {                                         \
        __syncthreads();                                                         \
        {                                                                        \
            const float* Ap = &A[(size_t)(m0 + srow) * K + k0 + scol];           \
            const float* Bp = &B[(size_t)(n0 + srow) * K + k0 + scol];           \
            float av[16], bv[16];                                                \
            _Pragma("unroll") for (int i = 0; i < 4; ++i) {                      \
                *(float4*)&av[i * 4] = *(const float4*)&Ap[i * 4];               \
                *(float4*)&bv[i * 4] = *(const float4*)&Bp[i * 4];               \
            }                                                                    \
            _Pragma("unroll") for (int hlf = 0; hlf < 2; ++hlf) {                \
                short8 HA, LA, HB, LB;                                           \
                _Pragma("unroll") for (int j = 0; j < 8; ++j) {                  \
                    float r;                                                     \
                    HA[j] = (short)split_hi(av[hlf * 8 + j], r);                 \
                    LA[j] = (short)rne16(r);                                     \
                    HB[j] = (short)split_hi(bv[hlf * 8 + j], r);                 \
                    LB[j] = (short)rne16(r);                                     \
                }                                                                \
                const int off = srow * GS + scol + hlf * 8;                      \
                *(short8*)&Ah[off] = HA;                                         \
                *(short8*)&Al[off] = LA;                                         \
                *(short8*)&Bh[off] = HB;                                         \
                *(short8*)&Bl[off] = LB;                                         \
            }                                                                    \
        }                                                                        \
        __syncthreads();                                                         \
        short8 a_h[4], a_l[4];                                                   \
        _Pragma("unroll") for (int mi = 0; mi < 4; ++mi) {                       \
            const int off = (mw + mi * 16 + l15) * GS + g * 8;                   \
            a_h[mi] = *(const short8*)&Ah[off];                                  \
            a_l[mi] = *(const short8*)&Al[off];                                  \
        }                                                                        \
        _Pragma("unroll") for (int ni = 0; ni < 4; ++ni) {                       \
            const int off = (nw + ni * 16 + l15) * GS + g * 8;                   \
            short8 b_h = *(const short8*)&Bh[off];                               \
            short8 b_l = *(const short8*)&Bl[off];                               \
            _Pragma("unroll") for (int mi = 0; mi < 4; ++mi) {                   \
                acc[mi][ni] = __builtin_amdgcn_mfma_f32_16x16x32_bf16(a_h[mi], b_h, acc[mi][ni], 0, 0, 0); \
                acc[mi][ni] = __builtin_amdgcn_mfma_f32_16x16x32_bf16(a_l[mi], b_h, acc[mi][ni], 0, 0, 0); \
                acc[mi][ni] = __builtin_amdgcn_mfma_f32_16x16x32_bf16(a_h[mi], b_l, acc[mi][ni], 0, 0, 0); \
            }                                                                    \
        }                                                                        \
    }                                                                            \
    EPILOGUE

// Out-projection: plain f32 + bias store.
__global__ __launch_bounds__(256)
void gemm_split_kernel(const float* __restrict__ A, const float* __restrict__ B,
                       const float* __restrict__ bias, float* __restrict__ C,
                       int M, int N, int K)
{
    GEMM_BODY({
        _Pragma("unroll") for (int ni = 0; ni < 4; ++ni) {
            const int col = n0 + nw + ni * 16 + l15;
            const float bb = bias[col];
            _Pragma("unroll") for (int mi = 0; mi < 4; ++mi) {
                const int row = m0 + mw + mi * 16 + 4 * g;
                _Pragma("unroll") for (int r = 0; r < 4; ++r)
                    C[(size_t)(row + r) * N + col] = acc[mi][ni][r] + bb;
            }
        }
    })
}

// QKV projection: writes Q/K as hi+lo bf16 split planes [B,N,1024],
// V transposed bf16 to Vt_g [B,H,128,2048].  Block's 128-col range lies
// entirely within one of {Q,K,V} (n0 multiple of 128, kinds at 1024-bounds).
__global__ __launch_bounds__(256)
void gemm_qkv_kernel(const float* __restrict__ A, const float* __restrict__ B,
                     const float* __restrict__ bias,
                     ushort* __restrict__ Qhi_g, ushort* __restrict__ Qlo_g,
                     ushort* __restrict__ Khi_g, ushort* __restrict__ Klo_g,
                     ushort* __restrict__ Vt_g,
                     int M, int N, int K)
{
    GEMM_BODY({
        const int kind = n0 >> 10;
        const int colbase = (n0 & 1023) + nw;
        if (kind < 2) {
            ushort* hi_g = (kind == 0) ? Qhi_g : Khi_g;
            ushort* lo_g = (kind == 0) ? Qlo_g : Klo_g;
            _Pragma("unroll") for (int ni = 0; ni < 4; ++ni) {
                const int colp = colbase + ni * 16 + l15;
                const float bb = bias[n0 + nw + ni * 16 + l15];
                _Pragma("unroll") for (int mi = 0; mi < 4; ++mi) {
                    const int row = m0 + mw + mi * 16 + 4 * g;
                    _Pragma("unroll") for (int r = 0; r < 4; ++r) {
                        float rem;
                        const float y = acc[mi][ni][r] + bb;
                        const ushort hb = split_hi(y, rem);
                        const ushort lb = rne16(rem);
                        const size_t idx = (size_t)(row + r) * DIM + colp;
                        hi_g[idx] = hb;
                        lo_g[idx] = lb;
                    }
                }
            }
        } else {
            // V: Vt_g[((b*8+h)*128+d)*2048 + n]; colp = h*128+d; 4 n-consec per store
            _Pragma("unroll") for (int ni = 0; ni < 4; ++ni) {
                const int colp = colbase + ni * 16 + l15;
                const float bb = bias[n0 + nw + ni * 16 + l15];
                _Pragma("unroll") for (int mi = 0; mi < 4; ++mi) {
                    const int row0 = m0 + mw + mi * 16 + 4 * g;
                    const unsigned p01 = (unsigned)rne16(acc[mi][ni][0] + bb)
                                       | ((unsigned)rne16(acc[mi][ni][1] + bb) << 16);
                    const unsigned p23 = (unsigned)rne16(acc[mi][ni][2] + bb)
                                       | ((unsigned)rne16(acc[mi][ni][3] + bb) << 16);
                    const size_t idx = ((size_t)((row0 >> 11) * 1024 + colp)) * SEQ
                                     + (row0 & 2047);
                    uint2 pk; pk.x = p01; pk.y = p23;
                    *(uint2*)&Vt_g[idx] = pk;
                }
            }
        }
    })
}

// ---------------------------------------------------------------------------
// MFMA flash attention v3.  Inputs: bf16 split planes from gemm_qkv.
// Block = (b,h,64 q-rows); 4 waves; KB=32 keys/iter, DOUBLE-BUFFERED LDS
// staged via global_load_lds w16 (linear LDS dest + pre-swizzled global src,
// m173).  One barrier per iter; loads issued a full phase ahead.
// K swizzle: col ^ (row&15)*8 (elems).  V swizzle: k ^ (d&3)*8.
// Frag contracts (m89, verified R1/R5/R7): A-frag row=lane&15, k=(lane>>4)*8+j;
// B-frag col=lane&15; D: col=lane&15, row=4*(lane>>4)+reg.
// ---------------------------------------------------------------------------
__global__ __launch_bounds__(256, 3)
void attn_mfma_kernel(const ushort* __restrict__ Qhi_g, const ushort* __restrict__ Qlo_g,
                      const ushort* __restrict__ Khi_g, const ushort* __restrict__ Klo_g,
                      const ushort* __restrict__ Vt_g, float* __restrict__ outp)
{
    constexpr int QB = 64, KB = 32, NT = SEQ / KB;   // 64 iterations
    constexpr int VS = 40;                           // Pl row stride
    __shared__ ushort KhiL[2][KB * HD];              // 2 x 8 KB
    __shared__ ushort KloL[2][KB * HD];              // 2 x 8 KB
    __shared__ ushort VtL[2][HD * KB];               // 2 x 8 KB
    __shared__ ushort Pl[QB * VS];                   // 5 KB

    const int tid  = threadIdx.x;
    const int lane = tid & 63;
    const int w    = tid >> 6;
    const int l15  = lane & 15;
    const int g    = lane >> 4;

    // XCD-aware swizzle (1024 blocks = 8 XCDs x 128)
    const int pid = blockIdx.x;
    const int lb  = (pid & 7) * 128 + (pid >> 3);
    const int qt  = lb & 31;
    const int bh_ = lb >> 5;
    const int h   = bh_ & 7, b = bh_ >> 3;
    const int q0  = qt * QB;

    // ---- Q -> registers: 2-way split A-frags from planes ----
    short8 qh[4], qlo[4];
    {
        const size_t qoff = (size_t)(b * SEQ + q0 + 16 * w + l15) * DIM + h * HD;
#pragma unroll
        for (int dc = 0; dc < 4; ++dc) {
            qh[dc]  = *(const short8*)&Qhi_g[qoff + dc * 32 + g * 8];
            qlo[dc] = *(const short8*)&Qlo_g[qoff + dc * 32 + g * 8];
        }
    }

    // ---- staging source pointers (per-lane, pre-swizzled) ----
    const ushort* kph[2]; const ushort* kpl[2]; const ushort* vpp[2];
    {
        const int kcol = l15 * 8;
#pragma unroll
        for (int i = 0; i < 2; ++i) {
            const int r_loc = 8 * w + 4 * i + g;        // g == lane>>4
            const int sc    = kcol ^ ((r_loc & 15) * 8);
            const size_t off = (size_t)(b * SEQ + r_loc) * DIM + h * HD + sc;
            kph[i] = Khi_g + off;
            kpl[i] = Klo_g + off;
        }
#pragma unroll
        for (int i = 0; i < 2; ++i) {
            const int d_loc = 32 * w + 16 * i + (lane >> 2);
            const int scv   = ((lane & 3) * 8) ^ ((d_loc & 3) * 8);
            vpp[i] = Vt_g + (size_t)((b * HEADS + h) * HD + d_loc) * SEQ + scv;
        }
    }

    float m_st[4], l_st[4];
#pragma unroll
    for (int r = 0; r < 4; ++r) { m_st[r] = -INFINITY; l_st[r] = 0.f; }
    f32x4 o[8];
#pragma unroll
    for (int n = 0; n < 8; ++n) o[n] = (f32x4){0.f, 0.f, 0.f, 0.f};

    // prologue: issue tile 0 into buf 0
#pragma unroll
    for (int i = 0; i < 2; ++i) {
        gload16(kph[i], &KhiL[0][(8 * w + 4 * i) * HD]);
        gload16(kpl[i], &KloL[0][(8 * w + 4 * i) * HD]);
        gload16(vpp[i], &VtL[0][(32 * w + 16 * i) * KB]);
        kph[i] += (size_t)KB * DIM; kpl[i] += (size_t)KB * DIM; vpp[i] += KB;
    }

    for (int kt = 0; kt < NT; ++kt) {
        const int cur = kt & 1;
        __syncthreads();   // drains this tile's loads; protects buf^1 reuse

        if (kt + 1 < NT) {
            const int nxt = cur ^ 1;
#pragma unroll
            for (int i = 0; i < 2; ++i) {
                gload16(kph[i], &KhiL[nxt][(8 * w + 4 * i) * HD]);
                gload16(kpl[i], &KloL[nxt][(8 * w + 4 * i) * HD]);
                gload16(vpp[i], &VtL[nxt][(32 * w + 16 * i) * KB]);
                kph[i] += (size_t)KB * DIM; kpl[i] += (size_t)KB * DIM; vpp[i] += KB;
            }
        }

        // ---- QK^T: S[16w.., 32k], 3 split products ----
        f32x4 sacc[2];
        sacc[0] = (f32x4){0.f, 0.f, 0.f, 0.f};
        sacc[1] = (f32x4){0.f, 0.f, 0.f, 0.f};
        __builtin_amdgcn_s_setprio(1);
#pragma unroll
        for (int dc = 0; dc < 4; ++dc) {
            const int sw = (dc * 32 + g * 8) ^ (l15 * 8);
#pragma unroll
            for (int n = 0; n < 2; ++n) {
                const int off = (n * 16 + l15) * HD + sw;
                short8 kh = *(const short8*)&KhiL[cur][off];
                short8 kl = *(const short8*)&KloL[cur][off];
                sacc[n] = __builtin_amdgcn_mfma_f32_16x16x32_bf16(qh[dc], kh, sacc[n], 0, 0, 0);
                sacc[n] = __builtin_amdgcn_mfma_f32_16x16x32_bf16(qh[dc], kl, sacc[n], 0, 0, 0);
                sacc[n] = __builtin_amdgcn_mfma_f32_16x16x32_bf16(qlo[dc], kh, sacc[n], 0, 0, 0);
            }
        }
        __builtin_amdgcn_s_setprio(0);

        // ---- online softmax (rows 16w + 4g + r) ----
        float alpha[4];
#pragma unroll
        for (int r = 0; r < 4; ++r) {
            float s0 = sacc[0][r] * SCALE_F;
            float s1 = sacc[1][r] * SCALE_F;
            float mx = fmaxf(s0, s1);
            mx = fmaxf(mx, __shfl_xor(mx, 1));
            mx = fmaxf(mx, __shfl_xor(mx, 2));
            mx = fmaxf(mx, __shfl_xor(mx, 4));
            mx = fmaxf(mx, __shfl_xor(mx, 8));
            const float mnew = fmaxf(m_st[r], mx);
            alpha[r] = __expf(m_st[r] - mnew);
            const float p0 = __expf(s0 - mnew);
            const float p1 = __expf(s1 - mnew);
            const int prow = (16 * w + 4 * g + r) * VS;
            Pl[prow + l15]      = rne16(p0);
            Pl[prow + 16 + l15] = rne16(p1);
            float ps = p0 + p1;
            ps += __shfl_xor(ps, 1);
            ps += __shfl_xor(ps, 2);
            ps += __shfl_xor(ps, 4);
            ps += __shfl_xor(ps, 8);
            l_st[r] = l_st[r] * alpha[r] + ps;
            m_st[r] = mnew;
        }
#pragma unroll
        for (int n = 0; n < 8; ++n)
#pragma unroll
            for (int r = 0; r < 4; ++r) o[n][r] *= alpha[r];

        // ---- PV ----
        __builtin_amdgcn_s_setprio(1);
        short8 pa = *(const short8*)&Pl[(16 * w + l15) * VS + g * 8];
#pragma unroll
        for (int n = 0; n < 8; ++n) {
            const int vrow = n * 16 + l15;
            short8 vbf = *(const short8*)&VtL[cur][vrow * KB + ((g * 8) ^ ((l15 & 3) * 8))];
            o[n] = __builtin_amdgcn_mfma_f32_16x16x32_bf16(pa, vbf, o[n], 0, 0, 0);
        }
        __builtin_amdgcn_s_setprio(0);
    }

    // ---- epilogue ----
    float rl[4];
#pragma unroll
    for (int r = 0; r < 4; ++r) rl[r] = 1.f / l_st[r];
    const size_t orow0 = (size_t)(b * SEQ + q0 + 16 * w + 4 * g);
#pragma unroll
    for (int n = 0; n < 8; ++n)
#pragma unroll
        for (int r = 0; r < 4; ++r)
            outp[(orow0 + r) * DIM + h * HD + n * 16 + l15] = o[n][r] * rl[r];
}

// ---------------------------------------------------------------------------
extern "C" void kernel_launch(void* const* d_in, const int* in_sizes, int n_in,
                              void* d_out, int out_size, void* d_ws, size_t ws_size,
                              hipStream_t stream)
{
    const float* x     = (const float*)d_in[0];
    const float* W_qkv = (const float*)d_in[1];
    const float* b_qkv = (const float*)d_in[2];
    const float* W0    = (const float*)d_in[3];
    const float* b0    = (const float*)d_in[4];
    float* out = (float*)d_out;

    const size_t PL = (size_t)BN_ROWS * DIM;          // 8 Mi elems per plane
    ushort* Qhi = (ushort*)d_ws;
    ushort* Qlo = Qhi + PL;
    ushort* Khi = Qhi + 2 * PL;
    ushort* Klo = Qhi + 3 * PL;
    ushort* Vt  = Qhi + 4 * PL;                       // [B,H,128,2048]
    float*  attn = (float*)(Qhi + 5 * PL);            // [8192,1024] f32

    // 1) QKV projection -> split planes (1536 blocks)
    gemm_qkv_kernel<<<dim3((BN_ROWS / 128) * (3 * DIM / 128)), 256, 0, stream>>>(
        x, W_qkv, b_qkv, Qhi, Qlo, Khi, Klo, Vt, BN_ROWS, 3 * DIM, DIM);

    // 2) attention -> attn [8192,1024]
    attn_mfma_kernel<<<dim3(BATCH * HEADS * (SEQ / 64)), 256, 0, stream>>>(
        Qhi, Qlo, Khi, Klo, Vt, attn);

    // 3) output projection (512 blocks)
    gemm_split_kernel<<<dim3((BN_ROWS / 128) * (DIM / 128)), 256, 0, stream>>>(
        attn, W0, b0, out, BN_ROWS, DIM, DIM);
}